// Round 1
// baseline (261.519 us; speedup 1.0000x reference)
//
#include <hip/hip_runtime.h>

#define NUM_NET 2
#define V 100000
#define D 128
#define B 4096
#define K 5
#define NS 10

// per-dot weights (sign encodes logsigmoid(+dot) vs logsigmoid(-dot))
#define W_MAIN_POS (1.0f/20480.0f)   // 1/(B*K)
#define W_INV_B    (1.0f/4096.0f)    // 1/B
#define HYP_B      (0.1f/4096.0f)    // HYP{1,2,3}/B (all 0.1)
#define HYP2_BK    (0.1f/20480.0f)   // HYP2/(B*K)

#define NBINS 64

__global__ __launch_bounds__(256) void rmne_main(
    const float* __restrict__ node_tables,
    const float* __restrict__ neigh_tables,
    const int*   __restrict__ nodes_idx,
    const int*   __restrict__ neigh_idx,
    const int*   __restrict__ role_idx,
    const int*   __restrict__ neg_main,
    const int*   __restrict__ neg_node,
    const int*   __restrict__ neg_cross,
    const int*   __restrict__ neg_role,
    float*       __restrict__ ws)
{
    const int tid  = threadIdx.x;
    const int lane = tid & 63;
    const int wave = tid >> 6;
    const int unit = blockIdx.x * 4 + wave;   // 8192 units total
    const int i = unit >> 12;                 // net index (0/1)
    const int b = unit & (B - 1);
    const int j = 1 - i;

    // ---- build the 144-entry dot list into 3 per-lane register slots ----
    // d = lane + 64*s; entries d in [0,143); d==143 is a zero-weight pad.
    int   pk[3];
    float wv[3];
    #pragma unroll
    for (int s = 0; s < 3; ++s) {
        int d = lane + 64 * s;
        int idx = 0; float w = 0.0f; int tab = 0;  // tab: 0/1 node net, 2/3 neigh net
        if      (d <   5) { idx = neigh_idx[(i*B + b)*K + d];              w =  W_MAIN_POS; tab = 2 + i; }
        else if (d <  55) { idx = neg_main[(i*B + b)*50 + (d-5)];          w = -W_INV_B;    tab = 2 + i; }
        else if (d <  56) { idx = nodes_idx[i*B + b];                      w =  HYP_B;      tab = j;     }
        else if (d <  66) { idx = neg_node[((i*2+j)*B + b)*NS + (d-56)];   w = -HYP_B;      tab = j;     }
        else if (d <  71) { idx = neigh_idx[(i*B + b)*K + (d-66)];         w =  HYP2_BK;    tab = 2 + j; }
        else if (d < 121) { idx = neg_cross[((i*2+j)*B + b)*50 + (d-71)];  w = -HYP_B;      tab = 2 + j; }
        else if (d < 122) { idx = role_idx[(i*2+0)*B + b];                 w =  HYP_B;      tab = 0;     }
        else if (d < 132) { idx = neg_role[((i*2+0)*B + b)*NS + (d-122)];  w = -HYP_B;      tab = 0;     }
        else if (d < 133) { idx = role_idx[(i*2+1)*B + b];                 w =  HYP_B;      tab = 1;     }
        else if (d < 143) { idx = neg_role[((i*2+1)*B + b)*NS + (d-133)];  w = -HYP_B;      tab = 1;     }
        pk[s] = idx | (tab << 20);
        wv[s] = w;
    }

    // ---- node embedding fragment: quarter-wave layout, 8 dims/lane ----
    const int l16     = lane & 15;
    const int quarter = lane >> 4;
    const int nrow    = nodes_idx[i*B + b];
    const float4* nep = (const float4*)(node_tables + ((size_t)i*V + (size_t)nrow)*D) + l16*2;
    const float4 ne0 = nep[0];
    const float4 ne1 = nep[1];

    float acc = 0.0f;

    auto do_iter = [&](int t, int pks, float wvs) {
        int   src = (4*t + quarter) & 63;
        int   p   = __shfl(pks, src, 64);
        float w   = __shfl(wvs, src, 64);
        int idx = p & 0xFFFFF;
        int tab = p >> 20;
        const float* base = (tab & 2) ? neigh_tables : node_tables;
        const float4* row = (const float4*)(base + ((size_t)(tab & 1)*V + (size_t)idx)*D) + l16*2;
        float4 c0 = row[0];
        float4 c1 = row[1];
        float pp = ne0.x*c0.x + ne0.y*c0.y + ne0.z*c0.z + ne0.w*c0.w
                 + ne1.x*c1.x + ne1.y*c1.y + ne1.z*c1.z + ne1.w*c1.w;
        // reduce within the 16-lane quarter (4 dots per wave in parallel)
        pp += __shfl_xor(pp, 1, 64);
        pp += __shfl_xor(pp, 2, 64);
        pp += __shfl_xor(pp, 4, 64);
        pp += __shfl_xor(pp, 8, 64);
        float x  = (w < 0.0f) ? -pp : pp;                       // sign folds the negation
        float ls = fminf(x, 0.0f) - __logf(1.0f + __expf(-fabsf(x)));
        acc += fabsf(w) * ls;
    };

    // slot index is wave-uniform within each section (d = 4t+q, 64 | 4*16)
    #pragma unroll 4
    for (int t = 0;  t < 16; ++t) do_iter(t, pk[0], wv[0]);
    #pragma unroll 4
    for (int t = 16; t < 32; ++t) do_iter(t, pk[1], wv[1]);
    #pragma unroll
    for (int t = 32; t < 36; ++t) do_iter(t, pk[2], wv[2]);

    // combine quarters: lanes within a quarter are identical, so xor16+xor32
    // adds exactly one representative from each quarter -> S_unit on all lanes.
    acc += __shfl_xor(acc, 16, 64);
    acc += __shfl_xor(acc, 32, 64);

    __shared__ float wsum[4];
    if (lane == 0) wsum[wave] = acc;
    __syncthreads();
    if (tid == 0) {
        float s = wsum[0] + wsum[1] + wsum[2] + wsum[3];
        atomicAdd(ws + (blockIdx.x & (NBINS - 1)), s);
    }
}

__global__ void rmne_finalize(const float* __restrict__ ws, float* __restrict__ out)
{
    float v = ws[threadIdx.x];
    v += __shfl_xor(v, 1, 64);
    v += __shfl_xor(v, 2, 64);
    v += __shfl_xor(v, 4, 64);
    v += __shfl_xor(v, 8, 64);
    v += __shfl_xor(v, 16, 64);
    v += __shfl_xor(v, 32, 64);
    if (threadIdx.x == 0) out[0] = v * (-1.0f / 10.0f);
}

extern "C" void kernel_launch(void* const* d_in, const int* in_sizes, int n_in,
                              void* d_out, int out_size, void* d_ws, size_t ws_size,
                              hipStream_t stream) {
    const float* node_tables  = (const float*)d_in[0];
    const float* neigh_tables = (const float*)d_in[1];
    const int*   nodes_idx    = (const int*)d_in[2];
    const int*   neigh_idx    = (const int*)d_in[3];
    const int*   role_idx     = (const int*)d_in[4];
    const int*   neg_main     = (const int*)d_in[5];
    const int*   neg_node     = (const int*)d_in[6];
    const int*   neg_cross    = (const int*)d_in[7];
    const int*   neg_role     = (const int*)d_in[8];
    float* ws  = (float*)d_ws;
    float* out = (float*)d_out;

    hipMemsetAsync(ws, 0, NBINS * sizeof(float), stream);
    rmne_main<<<2048, 256, 0, stream>>>(node_tables, neigh_tables, nodes_idx, neigh_idx,
                                        role_idx, neg_main, neg_node, neg_cross, neg_role, ws);
    rmne_finalize<<<1, 64, 0, stream>>>(ws, out);
}